// Round 3
// baseline (982.862 us; speedup 1.0000x reference)
//
#include <hip/hip_runtime.h>
#include <stdint.h>

// MHGCN: out = 0.5*(h1+h2); h1 = sym@(x@w0)+b0; h2 = sym@(h1@w1)+b1
// sym = (adj·rw) + (adj·rw)^T. N=8192, IN_F=256, OUT_F=128, R=2.
// Round 3: dtype-adaptive (probe kernel decides bf16 vs f32 inputs at runtime)
// and ws-size-adaptive (materialize sym if ws >= ~142MB, else on-the-fly).
// Internal compute: bf16 MFMA 16x16x32, f32 split-K atomic accumulation.
//
// ws layout:
//   [0,2MB)    xw0T  bf16 [128][8192]
//   [2,4MB)    hwT   bf16 [128][8192]
//   [4,8MB)    h1    f32  [8192][128]
//   [8,12MB)   h2    f32  [8192][128]
//   [12MB]     flag  int  (1 = inputs bf16, 0 = f32)
//   [13,141MB) sym   bf16 [8192][8192]   (fast path only)

#define NN 8192
#define KIN 256
#define FOUT 128
#define SPLITK 8
#define KCHUNK (NN / SPLITK)
#define LDP 40   // LDS row stride (32+8 pad): 80B = 20 banks, <=2-way = free

typedef __bf16 bf16x8 __attribute__((ext_vector_type(8)));
typedef float f32x4 __attribute__((ext_vector_type(4)));
typedef uint16_t u16x8 __attribute__((ext_vector_type(8)));

__device__ __forceinline__ float bf2f(uint16_t u) {
    union { uint32_t u; float f; } c; c.u = ((uint32_t)u) << 16; return c.f;
}
__device__ __forceinline__ uint16_t f2bf(float f) {
    union { float f; uint32_t u; } c; c.f = f;
    uint32_t r = c.u + 0x7fffu + ((c.u >> 16) & 1u);  // RNE
    return (uint16_t)(r >> 16);
}
__device__ __forceinline__ float combineAt(const void* adj, size_t idx,
                                           bool isbf, float r0, float r1) {
    if (isbf) {
        uint32_t u = ((const uint32_t*)adj)[idx];
        return bf2f((uint16_t)(u & 0xffffu)) * r0 + bf2f((uint16_t)(u >> 16)) * r1;
    } else {
        float2 v = ((const float2*)adj)[idx];
        return v.x * r0 + v.y * r1;
    }
}

// ---- probe: flag=1 if x_feature stored as bf16, 0 if f32 ----
// Even uint16 indices: bf16 storage -> sane exponents (~100% in [96,144]);
// f32 storage -> low mantissa halves, random exponents (~16% in range).
__global__ __launch_bounds__(256) void probe_kernel(
        const uint16_t* __restrict__ xr, int* __restrict__ flag) {
    __shared__ int cnt;
    if (threadIdx.x == 0) cnt = 0;
    __syncthreads();
    uint16_t v = xr[threadIdx.x * 16];   // even index, spans [0,4080]
    int e = (v >> 7) & 0xFF;
    if (e >= 96 && e <= 144) atomicAdd(&cnt, 1);
    __syncthreads();
    if (threadIdx.x == 0) flag[0] = (cnt >= 128) ? 1 : 0;
}

// ---- h1 = b0, h2 = b1 (GEMMs accumulate on top) ----
__global__ __launch_bounds__(256) void init_bias_kernel(
        const void* __restrict__ b0p, const void* __restrict__ b1p,
        float* __restrict__ h1, float* __restrict__ h2,
        const int* __restrict__ flag) {
    bool isbf = flag[0] != 0;
    int idx = (blockIdx.x * 256 + threadIdx.x) * 4;
    int f = idx & (FOUT - 1);
    float4 v0, v1;
    if (isbf) {
        const uint16_t* b0 = (const uint16_t*)b0p;
        const uint16_t* b1 = (const uint16_t*)b1p;
        v0 = make_float4(bf2f(b0[f]), bf2f(b0[f+1]), bf2f(b0[f+2]), bf2f(b0[f+3]));
        v1 = make_float4(bf2f(b1[f]), bf2f(b1[f+1]), bf2f(b1[f+2]), bf2f(b1[f+3]));
    } else {
        v0 = *(const float4*)((const float*)b0p + f);
        v1 = *(const float4*)((const float*)b1p + f);
    }
    *(float4*)(h1 + idx) = v0;
    *(float4*)(h2 + idx) = v1;
}

// ---- xw0T[f][j] = sum_k x[j][k]*w0[k][f], store transposed bf16 ----
__global__ __launch_bounds__(256) void xw0_kernel(
        const void* __restrict__ xp, const void* __restrict__ w0p,
        uint16_t* __restrict__ xw0T, const int* __restrict__ flag) {
    bool isbf = flag[0] != 0;
    int t = blockIdx.x * 256 + threadIdx.x;   // 131072 threads
    int j = t >> 4;
    int f0 = (t & 15) * 8;
    float acc[8] = {0.f,0.f,0.f,0.f,0.f,0.f,0.f,0.f};
    if (isbf) {
        const uint16_t* xrow = (const uint16_t*)xp + (size_t)j * KIN;
        const uint16_t* w0 = (const uint16_t*)w0p;
        for (int k8 = 0; k8 < KIN; k8 += 8) {
            u16x8 xv = *(const u16x8*)(xrow + k8);
            #pragma unroll
            for (int i = 0; i < 8; i++) {
                float a = bf2f(xv[i]);
                u16x8 wv = *(const u16x8*)(w0 + (size_t)(k8 + i) * FOUT + f0);
                #pragma unroll
                for (int q = 0; q < 8; q++) acc[q] += a * bf2f(wv[q]);
            }
        }
    } else {
        const float* xrow = (const float*)xp + (size_t)j * KIN;
        const float* w0 = (const float*)w0p;
        for (int k4 = 0; k4 < KIN; k4 += 4) {
            float4 xv = *(const float4*)(xrow + k4);
            float xa[4] = {xv.x, xv.y, xv.z, xv.w};
            #pragma unroll
            for (int i = 0; i < 4; i++) {
                const float* wr = w0 + (size_t)(k4 + i) * FOUT + f0;
                float4 wa = *(const float4*)wr;
                float4 wb = *(const float4*)(wr + 4);
                acc[0] += xa[i]*wa.x; acc[1] += xa[i]*wa.y;
                acc[2] += xa[i]*wa.z; acc[3] += xa[i]*wa.w;
                acc[4] += xa[i]*wb.x; acc[5] += xa[i]*wb.y;
                acc[6] += xa[i]*wb.z; acc[7] += xa[i]*wb.w;
            }
        }
    }
    #pragma unroll
    for (int q = 0; q < 8; q++) xw0T[(size_t)(f0 + q) * NN + j] = f2bf(acc[q]);
}

// ---- sym[i][j] = bf16(adjC[i][j] + adjC[j][i]), paired 64x64 tiles ----
__global__ __launch_bounds__(256) void sym_kernel(
        const void* __restrict__ adj, const void* __restrict__ rwp,
        uint16_t* __restrict__ sym, const int* __restrict__ flag) {
    int I = blockIdx.x, J = blockIdx.y;
    if (J < I) return;
    bool isbf = flag[0] != 0;
    float r0 = isbf ? bf2f(((const uint16_t*)rwp)[0]) : ((const float*)rwp)[0];
    float r1 = isbf ? bf2f(((const uint16_t*)rwp)[1]) : ((const float*)rwp)[1];
    __shared__ float Ds[64][65];
    __shared__ float Es[64][65];
    int i0 = I * 64, j0 = J * 64;
    int t = threadIdx.x;
    #pragma unroll
    for (int s = 0; s < 16; s++) {
        int q = s * 256 + t;
        int a = q >> 6, b = q & 63;
        Ds[a][b] = combineAt(adj, (size_t)(i0 + a) * NN + (j0 + b), isbf, r0, r1);
        Es[a][b] = combineAt(adj, (size_t)(j0 + a) * NN + (i0 + b), isbf, r0, r1);
    }
    __syncthreads();
    if (I == J) {
        #pragma unroll
        for (int s = 0; s < 16; s++) {
            int q = s * 256 + t;
            int a = q >> 6, b = q & 63;
            sym[(size_t)(i0 + a) * NN + (j0 + b)] = f2bf(Ds[a][b] + Es[b][a]);
        }
    } else {
        #pragma unroll
        for (int s = 0; s < 16; s++) {
            int q = s * 256 + t;
            int a = q >> 6, b = q & 63;
            sym[(size_t)(i0 + a) * NN + (j0 + b)] = f2bf(Ds[a][b] + Es[b][a]);
            sym[(size_t)(j0 + a) * NN + (i0 + b)] = f2bf(Es[a][b] + Ds[b][a]);
        }
    }
}

// ---- fast GEMM: out[m][:] += sym[m][k0:k0+KCHUNK] @ BT^T (split-K atomics) ----
__global__ __launch_bounds__(256) void gemm_atomic_kernel(
        const uint16_t* __restrict__ A, const uint16_t* __restrict__ BT,
        float* __restrict__ out) {
    __shared__ __align__(16) uint16_t As[128 * LDP];
    __shared__ __align__(16) uint16_t Bs[128 * LDP];
    const int m0 = blockIdx.x * 128;
    const int k0 = blockIdx.y * KCHUNK;
    const int t = threadIdx.x;
    const int w = t >> 6;
    const int L = t & 63;
    const int mb = (w & 1) * 64;
    const int nb = (w >> 1) * 64;
    const int fr_l = L & 15;
    const int fr_k = (L >> 4) * 8;
    const int sr = t >> 2;
    const int sk = (t & 3) * 8;

    f32x4 acc[4][4];
    #pragma unroll
    for (int r = 0; r < 4; r++)
        #pragma unroll
        for (int c = 0; c < 4; c++)
            acc[r][c] = (f32x4){0.f, 0.f, 0.f, 0.f};

    for (int kk = 0; kk < KCHUNK; kk += 32) {
        const int kg = k0 + kk;
        uint4 av0 = *(const uint4*)(A + (size_t)(m0 + sr) * NN + kg + sk);
        uint4 av1 = *(const uint4*)(A + (size_t)(m0 + 64 + sr) * NN + kg + sk);
        uint4 bv0 = *(const uint4*)(BT + (size_t)sr * NN + kg + sk);
        uint4 bv1 = *(const uint4*)(BT + (size_t)(64 + sr) * NN + kg + sk);
        __syncthreads();
        *(uint4*)(As + sr * LDP + sk) = av0;
        *(uint4*)(As + (64 + sr) * LDP + sk) = av1;
        *(uint4*)(Bs + sr * LDP + sk) = bv0;
        *(uint4*)(Bs + (64 + sr) * LDP + sk) = bv1;
        __syncthreads();

        bf16x8 af[4], bf[4];
        #pragma unroll
        for (int r = 0; r < 4; r++)
            af[r] = *(const bf16x8*)(As + (mb + r * 16 + fr_l) * LDP + fr_k);
        #pragma unroll
        for (int c = 0; c < 4; c++)
            bf[c] = *(const bf16x8*)(Bs + (nb + c * 16 + fr_l) * LDP + fr_k);
        #pragma unroll
        for (int r = 0; r < 4; r++)
            #pragma unroll
            for (int c = 0; c < 4; c++)
                acc[r][c] = __builtin_amdgcn_mfma_f32_16x16x32_bf16(af[r], bf[c], acc[r][c], 0, 0, 0);
    }

    #pragma unroll
    for (int r = 0; r < 4; r++)
        #pragma unroll
        for (int c = 0; c < 4; c++) {
            int col = nb + c * 16 + (L & 15);
            int rowb = m0 + mb + r * 16 + (L >> 4) * 4;
            #pragma unroll
            for (int q = 0; q < 4; q++)
                atomicAdd(out + (size_t)(rowb + q) * FOUT + col, acc[r][c][q]);
        }
}

// ---- fallback GEMM: stages sym tile on the fly from raw adj ----
__global__ __launch_bounds__(256) void gemm_otf_kernel(
        const void* __restrict__ adj, const uint16_t* __restrict__ BT,
        float* __restrict__ out, const void* __restrict__ rwp,
        const int* __restrict__ flag) {
    bool isbf = flag[0] != 0;
    float r0 = isbf ? bf2f(((const uint16_t*)rwp)[0]) : ((const float*)rwp)[0];
    float r1 = isbf ? bf2f(((const uint16_t*)rwp)[1]) : ((const float*)rwp)[1];
    __shared__ __align__(16) uint16_t As[128 * LDP];
    __shared__ __align__(16) uint16_t Bs[128 * LDP];
    const int m0 = blockIdx.x * 128;
    const int k0 = blockIdx.y * KCHUNK;
    const int t = threadIdx.x;
    const int w = t >> 6;
    const int L = t & 63;
    const int mb = (w & 1) * 64;
    const int nb = (w >> 1) * 64;
    const int fr_l = L & 15;
    const int fr_k = (L >> 4) * 8;
    const int sr = t >> 2;
    const int sk = (t & 3) * 8;

    f32x4 acc[4][4];
    #pragma unroll
    for (int r = 0; r < 4; r++)
        #pragma unroll
        for (int c = 0; c < 4; c++)
            acc[r][c] = (f32x4){0.f, 0.f, 0.f, 0.f};

    for (int kk = 0; kk < KCHUNK; kk += 32) {
        const int kg = k0 + kk;
        uint4 bv0 = *(const uint4*)(BT + (size_t)sr * NN + kg + sk);
        uint4 bv1 = *(const uint4*)(BT + (size_t)(64 + sr) * NN + kg + sk);
        __syncthreads();   // prior iter's fragment reads done
        *(uint4*)(Bs + sr * LDP + sk) = bv0;
        *(uint4*)(Bs + (64 + sr) * LDP + sk) = bv1;
        // pass 1: row side, m-major (coalesced over k)
        #pragma unroll
        for (int s = 0; s < 16; s++) {
            int idx = s * 256 + t;
            int m = idx >> 5, k = idx & 31;
            As[m * LDP + k] = f2bf(combineAt(adj, (size_t)(m0 + m) * NN + (kg + k), isbf, r0, r1));
        }
        __syncthreads();   // pass1 visible
        // pass 2: transpose side, k-major (coalesced over m)
        #pragma unroll
        for (int s = 0; s < 16; s++) {
            int idx = s * 256 + t;
            int k = idx >> 7, m = idx & 127;
            float v2 = combineAt(adj, (size_t)(kg + k) * NN + (m0 + m), isbf, r0, r1);
            As[m * LDP + k] = f2bf(bf2f(As[m * LDP + k]) + v2);
        }
        __syncthreads();   // staging complete

        bf16x8 af[4], bf[4];
        #pragma unroll
        for (int r = 0; r < 4; r++)
            af[r] = *(const bf16x8*)(As + (mb + r * 16 + fr_l) * LDP + fr_k);
        #pragma unroll
        for (int c = 0; c < 4; c++)
            bf[c] = *(const bf16x8*)(Bs + (nb + c * 16 + fr_l) * LDP + fr_k);
        #pragma unroll
        for (int r = 0; r < 4; r++)
            #pragma unroll
            for (int c = 0; c < 4; c++)
                acc[r][c] = __builtin_amdgcn_mfma_f32_16x16x32_bf16(af[r], bf[c], acc[r][c], 0, 0, 0);
    }

    #pragma unroll
    for (int r = 0; r < 4; r++)
        #pragma unroll
        for (int c = 0; c < 4; c++) {
            int col = nb + c * 16 + (L & 15);
            int rowb = m0 + mb + r * 16 + (L >> 4) * 4;
            #pragma unroll
            for (int q = 0; q < 4; q++)
                atomicAdd(out + (size_t)(rowb + q) * FOUT + col, acc[r][c][q]);
        }
}

// ---- hwT[f][j] = sum_k h1[j][k]*w1[k][f], store transposed bf16 ----
__global__ __launch_bounds__(256) void h1w1_kernel(
        const float* __restrict__ h1, const void* __restrict__ w1p,
        uint16_t* __restrict__ hwT, const int* __restrict__ flag) {
    bool isbf = flag[0] != 0;
    int t = blockIdx.x * 256 + threadIdx.x;
    int j = t >> 4;
    int f0 = (t & 15) * 8;
    float acc[8] = {0.f,0.f,0.f,0.f,0.f,0.f,0.f,0.f};
    const float* hrow = h1 + (size_t)j * FOUT;
    if (isbf) {
        const uint16_t* w1 = (const uint16_t*)w1p;
        for (int k4 = 0; k4 < FOUT; k4 += 4) {
            float4 a4 = *(const float4*)(hrow + k4);
            float av[4] = {a4.x, a4.y, a4.z, a4.w};
            #pragma unroll
            for (int i = 0; i < 4; i++) {
                u16x8 wv = *(const u16x8*)(w1 + (size_t)(k4 + i) * FOUT + f0);
                #pragma unroll
                for (int q = 0; q < 8; q++) acc[q] += av[i] * bf2f(wv[q]);
            }
        }
    } else {
        const float* w1 = (const float*)w1p;
        for (int k4 = 0; k4 < FOUT; k4 += 4) {
            float4 a4 = *(const float4*)(hrow + k4);
            float av[4] = {a4.x, a4.y, a4.z, a4.w};
            #pragma unroll
            for (int i = 0; i < 4; i++) {
                const float* wr = w1 + (size_t)(k4 + i) * FOUT + f0;
                float4 wa = *(const float4*)wr;
                float4 wb = *(const float4*)(wr + 4);
                acc[0] += av[i]*wa.x; acc[1] += av[i]*wa.y;
                acc[2] += av[i]*wa.z; acc[3] += av[i]*wa.w;
                acc[4] += av[i]*wb.x; acc[5] += av[i]*wb.y;
                acc[6] += av[i]*wb.z; acc[7] += av[i]*wb.w;
            }
        }
    }
    #pragma unroll
    for (int q = 0; q < 8; q++) hwT[(size_t)(f0 + q) * NN + j] = f2bf(acc[q]);
}

// ---- out = 0.5*(h1+h2), dtype per flag ----
__global__ __launch_bounds__(256) void final_kernel(
        const float* __restrict__ h1, const float* __restrict__ h2,
        void* __restrict__ outp, const int* __restrict__ flag) {
    int idx = (blockIdx.x * 256 + threadIdx.x) * 4;
    float4 a = *(const float4*)(h1 + idx);
    float4 b = *(const float4*)(h2 + idx);
    float4 r = make_float4(0.5f*(a.x+b.x), 0.5f*(a.y+b.y), 0.5f*(a.z+b.z), 0.5f*(a.w+b.w));
    if (flag[0] != 0) {
        ushort4 ov = make_ushort4(f2bf(r.x), f2bf(r.y), f2bf(r.z), f2bf(r.w));
        *(ushort4*)((uint16_t*)outp + idx) = ov;
    } else {
        *(float4*)((float*)outp + idx) = r;
    }
}

extern "C" void kernel_launch(void* const* d_in, const int* in_sizes, int n_in,
                              void* d_out, int out_size, void* d_ws, size_t ws_size,
                              hipStream_t stream) {
    char* ws = (char*)d_ws;
    uint16_t* xw0T = (uint16_t*)(ws);
    uint16_t* hwT  = (uint16_t*)(ws + (2u << 20));
    float*    h1   = (float*)   (ws + (4u << 20));
    float*    h2   = (float*)   (ws + (8u << 20));
    int*      flag = (int*)     (ws + (12u << 20));
    uint16_t* sym  = (uint16_t*)(ws + (13u << 20));
    const size_t need_fast = ((size_t)13 << 20) + (size_t)NN * NN * 2;  // ~141 MB
    const bool fast = ws_size >= need_fast;

    probe_kernel<<<1, 256, 0, stream>>>((const uint16_t*)d_in[0], flag);
    init_bias_kernel<<<1024, 256, 0, stream>>>(d_in[3], d_in[5], h1, h2, flag);
    xw0_kernel<<<512, 256, 0, stream>>>(d_in[0], d_in[2], xw0T, flag);
    if (fast) {
        sym_kernel<<<dim3(128, 128), 256, 0, stream>>>(d_in[1], d_in[6], sym, flag);
        gemm_atomic_kernel<<<dim3(64, SPLITK), 256, 0, stream>>>(sym, xw0T, h1);
    } else {
        gemm_otf_kernel<<<dim3(64, SPLITK), 256, 0, stream>>>(d_in[1], xw0T, h1, d_in[6], flag);
    }
    h1w1_kernel<<<512, 256, 0, stream>>>(h1, d_in[4], hwT, flag);
    if (fast) {
        gemm_atomic_kernel<<<dim3(64, SPLITK), 256, 0, stream>>>(sym, hwT, h2);
    } else {
        gemm_otf_kernel<<<dim3(64, SPLITK), 256, 0, stream>>>(d_in[1], hwT, h2, d_in[6], flag);
    }
    final_kernel<<<1024, 256, 0, stream>>>(h1, h2, d_out, flag);
}